// Round 4
// baseline (828.632 us; speedup 1.0000x reference)
//
#include <hip/hip_runtime.h>

// Problem constants (fixed by the reference)
#define NN   50000
#define EE   800000
#define DD   64
#define HH   128
#define KIN  320          // 5 * 64
#define TILE_E 32         // 32 edges/block -> LDS 20480 B -> 8 blocks/CU

typedef __bf16 bf16x8 __attribute__((ext_vector_type(8)));
typedef float  f32x4  __attribute__((ext_vector_type(4)));

#if __has_builtin(__builtin_amdgcn_cvt_pk_bf16_f32)
typedef __bf16 bf16x2_t __attribute__((ext_vector_type(2)));
__device__ __forceinline__ unsigned int pk2(float a, float b) {
  union { bf16x2_t v; unsigned int u; } cv;
  cv.v = __builtin_amdgcn_cvt_pk_bf16_f32(a, b);
  return cv.u;
}
__device__ __forceinline__ unsigned short f2bf(float a) {
  return (unsigned short)(pk2(a, a) & 0xFFFFu);
}
#else
__device__ __forceinline__ unsigned short f2bf(float f) {
  union { float f; unsigned int u; } v; v.f = f;
  unsigned int u = v.u + 0x7FFFu + ((v.u >> 16) & 1u);   // RTNE
  return (unsigned short)(u >> 16);
}
__device__ __forceinline__ unsigned int pk2(float a, float b) {
  return (unsigned int)f2bf(a) | ((unsigned int)f2bf(b) << 16);
}
#endif

__device__ __forceinline__ float bf2f(unsigned short b) {
  union { unsigned int u; float f; } v; v.u = ((unsigned int)b) << 16; return v.f;
}

// Packed, pad-free psi layout in 16B units: unit = (mt*10 + k0)*64 + row15*4 + quad
// u16 index for (row in [0,32), kk in [0,320)):
__device__ __forceinline__ int psiIdx(int row, int kk) {
  return ((((row >> 4) * 10 + (kk >> 5)) << 6) + ((row & 15) << 2) + ((kk >> 3) & 3)) * 8
         + (kk & 7);
}

// ---------------------------------------------------------------------------
// Fused prep: node tables fp32->bf16, weight transpose fp32->bf16, receiver
// histogram, agg zeroing. Grid 3381 x 256 (3125 table blocks + 256 weight).
// ---------------------------------------------------------------------------
__global__ __launch_bounds__(256) void prep_all(
    const float* __restrict__ hd, const float* __restrict__ hs,
    const float* __restrict__ W0, const float* __restrict__ W1,
    const float* __restrict__ W2, const int* __restrict__ rcv,
    unsigned short* __restrict__ hdb, unsigned short* __restrict__ hsb,
    unsigned short* __restrict__ WT0, unsigned short* __restrict__ WT1,
    unsigned short* __restrict__ WT2,
    int* __restrict__ cnt, float* __restrict__ agg) {
  int b = blockIdx.x;
  int t = b * 256 + threadIdx.x;
  if (b < 3125) {                          // t in [0, 800000)
    atomicAdd(&cnt[rcv[t]], 1);            // histogram for counting sort
    *(float4*)(agg + (size_t)t * 4) = (float4){0.f, 0.f, 0.f, 0.f};  // zero agg
    const int n = NN * DD / 8;             // 400000
    const float* src; unsigned short* dst; int i;
    if (t < n) { src = hd; dst = hdb; i = t; }
    else       { src = hs; dst = hsb; i = t - n; }
    float4 a = *(const float4*)(src + (size_t)i * 8);
    float4 c = *(const float4*)(src + (size_t)i * 8 + 4);
    uint4 w;
    w.x = pk2(a.x, a.y); w.y = pk2(a.z, a.w);
    w.z = pk2(c.x, c.y); w.w = pk2(c.z, c.w);
    *(uint4*)(dst + (size_t)i * 8) = w;
  } else {                                 // weights: u in [0, 65536)
    int u = t - 3125 * 256;
    if (u < KIN * HH) {
      int k = u / HH, n2 = u % HH;
      WT0[n2 * KIN + k] = f2bf(W0[u]);
    } else if (u < KIN * HH + HH * HH) {
      int v = u - KIN * HH; int k = v / HH, n2 = v % HH;
      WT1[n2 * HH + k] = f2bf(W1[v]);
    } else {
      int v = u - KIN * HH - HH * HH; int k = v / DD, n2 = v % DD;
      WT2[n2 * HH + k] = f2bf(W2[v]);
    }
  }
}

// ---------------------------------------------------------------------------
// Exclusive prefix sum over cnt[50000] in place. One block, 1024 threads.
// ---------------------------------------------------------------------------
__global__ __launch_bounds__(1024) void scan_bins(int* __restrict__ cnt) {
  __shared__ int ts[1024];
  const int C = 49;                       // 1024*49 >= 50000
  int t = threadIdx.x;
  int base = t * C;
  int s = 0;
  for (int i = 0; i < C; ++i) { int idx = base + i; if (idx < NN) s += cnt[idx]; }
  ts[t] = s;
  __syncthreads();
  for (int d = 1; d < 1024; d <<= 1) {    // Hillis-Steele inclusive scan
    int v = (t >= d) ? ts[t - d] : 0;
    __syncthreads();
    ts[t] += v;
    __syncthreads();
  }
  int run = (t == 0) ? 0 : ts[t - 1];
  for (int i = 0; i < C; ++i) {
    int idx = base + i;
    if (idx < NN) { int c = cnt[idx]; cnt[idx] = run; run += c; }
  }
}

// ---------------------------------------------------------------------------
// Counting-sort scatter: perm only (sorted -> orig edge id). snd/rcv are
// re-derived in edge_mlp via L2-hit hops (saves 2 random-write arrays).
// ---------------------------------------------------------------------------
__global__ __launch_bounds__(256) void scatter_perm(
    const int* __restrict__ rcv,
    const int* __restrict__ cnt, int* __restrict__ cursor,
    int* __restrict__ perm) {
  int e = blockIdx.x * 256 + threadIdx.x;
  int r = rcv[e];
  int pos = cnt[r] + atomicAdd(&cursor[r], 1);
  perm[pos] = e;
}

// ---------------------------------------------------------------------------
// Fused edge kernel, receiver-sorted order. 256 threads (4 waves), 32 edges/
// block, LDS = 20480 B -> 8 blocks/CU (round-1 measured 91% occupancy at this
// shape, VGPR=32). Sorted receivers => run-merged atomic scatter and
// block-local receiver gathers; bytes stay at the round-2 level.
// ---------------------------------------------------------------------------
__global__ __launch_bounds__(256, 8) void edge_mlp(
    const unsigned short* __restrict__ hdb,  // h_d_prev [N][64] bf16
    const unsigned short* __restrict__ hsb,  // h_s      [N][64] bf16
    const float* __restrict__ ef,            // edge_feat[E][64] fp32
    const int* __restrict__ perm,            // sorted -> original edge id
    const int* __restrict__ snd,
    const int* __restrict__ rcv,
    const unsigned short* __restrict__ WT0,  // [128][320] bf16
    const float* __restrict__ b0,            // [128]
    const unsigned short* __restrict__ WT1,  // [128][128] bf16
    const float* __restrict__ b1,            // [128]
    const unsigned short* __restrict__ WT2,  // [64][128] bf16
    const float* __restrict__ b2,            // [64]
    float* __restrict__ agg)                 // [N][64] fp32
{
  __shared__ __align__(16) unsigned short psi[TILE_E * KIN];  // 20480 B exactly

  const int tid  = threadIdx.x;
  const int e0   = blockIdx.x * TILE_E;
  const int wv   = tid >> 6;
  const int lane = tid & 63;
  const int ln   = lane & 15;
  const int quad = lane >> 4;

  // Receiver for the merge phase (dependent chain hidden under the gather).
  int myr = 0;
  if (tid < TILE_E) myr = rcv[perm[e0 + tid]];

  // Gather. 5 segs x 32 edges x 8 chunks: e = tid>>3, c = tid&7 (16B chunk).
  // segs 0-3: bf16 table rows. seg 4: ef fp32 (via perm), pack to bf16.
  {
    const int e  = tid >> 3;
    const int c  = tid & 7;
    const int pe = perm[e0 + e];           // L1-broadcast across 8 threads
    const int si = snd[pe];
    const int ri = rcv[pe];
    #pragma unroll
    for (int seg = 0; seg < 5; ++seg) {
      int unit = (((e >> 4) * 10 + seg * 2 + (c >> 2)) << 6) + ((e & 15) << 2) + (c & 3);
      uint4 w;
      if (seg < 4) {
        const unsigned short* tb = (seg & 2) ? hdb : hsb;   // 0,1=h_s  2,3=h_d
        int ix = (seg & 1) ? ri : si;
        w = *(const uint4*)(tb + (size_t)ix * DD + c * 8);
      } else {
        const float* src = ef + (size_t)pe * DD;
        float4 v0 = *(const float4*)(src + c * 8);
        float4 v1 = *(const float4*)(src + c * 8 + 4);
        w.x = pk2(v0.x, v0.y); w.y = pk2(v0.z, v0.w);
        w.z = pk2(v1.x, v1.y); w.w = pk2(v1.z, v1.w);
      }
      *(uint4*)(&psi[unit * 8]) = w;
    }
  }
  __syncthreads();

  f32x4 acc0[2], acc1[2];

  // ------------------ Layer 0: [32,320] @ [320,128] ------------------------
  {
    #pragma unroll
    for (int m = 0; m < 2; ++m) { acc0[m] = (f32x4){0,0,0,0}; acc1[m] = (f32x4){0,0,0,0}; }
    const unsigned short* wb0 = WT0 + (wv * 32 + ln) * KIN + quad * 8;
    const unsigned short* wb1 = wb0 + 16 * KIN;
    #pragma unroll
    for (int k0 = 0; k0 < 10; ++k0) {
      bf16x8 bf0 = *(const bf16x8*)(wb0 + k0 * 32);
      bf16x8 bf1 = *(const bf16x8*)(wb1 + k0 * 32);
      #pragma unroll
      for (int mt = 0; mt < 2; ++mt) {
        bf16x8 af = *(const bf16x8*)(&psi[(((mt * 10 + k0) << 6) + (ln << 2) + quad) * 8]);
        acc0[mt] = __builtin_amdgcn_mfma_f32_16x16x32_bf16(af, bf0, acc0[mt], 0, 0, 0);
        acc1[mt] = __builtin_amdgcn_mfma_f32_16x16x32_bf16(af, bf1, acc1[mt], 0, 0, 0);
      }
    }
  }
  __syncthreads();          // psi input reads done -> safe to overwrite kk[0,128)

  // h1 -> kk [0,128)
  {
    float bv0 = b0[wv * 32 + ln];
    float bv1 = b0[wv * 32 + 16 + ln];
    #pragma unroll
    for (int mt = 0; mt < 2; ++mt) {
      #pragma unroll
      for (int i = 0; i < 4; ++i) {
        int base = ((mt * 10 + wv) << 6) + ((quad * 4 + i) << 2) + (ln >> 3);
        float v0 = acc0[mt][i] + bv0; v0 = v0 > 0.f ? v0 : 0.f;
        float v1 = acc1[mt][i] + bv1; v1 = v1 > 0.f ? v1 : 0.f;
        psi[base * 8 + (ln & 7)]       = f2bf(v0);
        psi[(base + 2) * 8 + (ln & 7)] = f2bf(v1);
      }
    }
  }
  __syncthreads();

  // ------------------ Layer 1: [32,128] @ [128,128] ------------------------
  {
    #pragma unroll
    for (int m = 0; m < 2; ++m) { acc0[m] = (f32x4){0,0,0,0}; acc1[m] = (f32x4){0,0,0,0}; }
    const unsigned short* wb0 = WT1 + (wv * 32 + ln) * HH + quad * 8;
    const unsigned short* wb1 = wb0 + 16 * HH;
    #pragma unroll
    for (int k0 = 0; k0 < 4; ++k0) {
      bf16x8 bf0 = *(const bf16x8*)(wb0 + k0 * 32);
      bf16x8 bf1 = *(const bf16x8*)(wb1 + k0 * 32);
      #pragma unroll
      for (int mt = 0; mt < 2; ++mt) {
        bf16x8 af = *(const bf16x8*)(&psi[(((mt * 10 + k0) << 6) + (ln << 2) + quad) * 8]);
        acc0[mt] = __builtin_amdgcn_mfma_f32_16x16x32_bf16(af, bf0, acc0[mt], 0, 0, 0);
        acc1[mt] = __builtin_amdgcn_mfma_f32_16x16x32_bf16(af, bf1, acc1[mt], 0, 0, 0);
      }
    }
  }
  __syncthreads();          // h1 reads done -> overwrite with h2

  {
    float bv0 = b1[wv * 32 + ln];
    float bv1 = b1[wv * 32 + 16 + ln];
    #pragma unroll
    for (int mt = 0; mt < 2; ++mt) {
      #pragma unroll
      for (int i = 0; i < 4; ++i) {
        int base = ((mt * 10 + wv) << 6) + ((quad * 4 + i) << 2) + (ln >> 3);
        float v0 = acc0[mt][i] + bv0; v0 = v0 > 0.f ? v0 : 0.f;
        float v1 = acc1[mt][i] + bv1; v1 = v1 > 0.f ? v1 : 0.f;
        psi[base * 8 + (ln & 7)]       = f2bf(v0);
        psi[(base + 2) * 8 + (ln & 7)] = f2bf(v1);
      }
    }
  }
  __syncthreads();

  // ---- Layer 2: [32,128] @ [128,64] + s_ij + run-merged atomic scatter ----
  {
    f32x4 acc[2];
    #pragma unroll
    for (int m = 0; m < 2; ++m) acc[m] = (f32x4){0,0,0,0};
    const unsigned short* wb = WT2 + (wv * 16 + ln) * HH + quad * 8;
    #pragma unroll
    for (int k0 = 0; k0 < 4; ++k0) {
      bf16x8 bf = *(const bf16x8*)(wb + k0 * 32);
      #pragma unroll
      for (int mt = 0; mt < 2; ++mt) {
        bf16x8 af = *(const bf16x8*)(&psi[(((mt * 10 + k0) << 6) + (ln << 2) + quad) * 8]);
        acc[mt] = __builtin_amdgcn_mfma_f32_16x16x32_bf16(af, bf, acc[mt], 0, 0, 0);
      }
    }
    int   col = wv * 16 + ln;   // waves 0..3 cover cols 0..63
    float bv  = b2[col];
    float sv[8];
    #pragma unroll
    for (int mt = 0; mt < 2; ++mt) {
      #pragma unroll
      for (int i = 0; i < 4; ++i) {
        int row = mt * 16 + quad * 4 + i;
        float p  = acc[mt][i] + bv; p = p > 0.f ? p : 0.f;
        float di = bf2f(psi[psiIdx(row, 128 + col)]);
        float dj = bf2f(psi[psiIdx(row, 192 + col)]);
        sv[mt * 4 + i] = p * (dj - di);
      }
    }
    __syncthreads();          // all psi reads done -> overlay s-tile + rt

    float* st = (float*)psi;                   // [32][64] fp32, 8192 B
    int*   rt = (int*)(psi + 4096);            // 32 ints at byte 8192
    #pragma unroll
    for (int mt = 0; mt < 2; ++mt) {
      #pragma unroll
      for (int i = 0; i < 4; ++i) {
        int row = mt * 16 + quad * 4 + i;      // (row>>2)&3 == quad
        st[row * 64 + (col ^ (quad << 3))] = sv[mt * 4 + i];
      }
    }
    if (tid < TILE_E) rt[tid] = myr;
    __syncthreads();

    // Thread t: column c2 = t&63, rows [wv*8, wv*8+8), sorted receivers.
    // rt[row] is wave-uniform per step -> no divergence in the run-merge.
    int c2  = tid & 63;
    int rr0 = (tid >> 6) * 8;
    float a  = 0.f;
    int  prev = rt[rr0];
    #pragma unroll
    for (int j = 0; j < 8; ++j) {
      int row = rr0 + j;
      int rc  = rt[row];
      float v = st[row * 64 + (c2 ^ ((((unsigned)row >> 2) & 3) << 3))];
      if (rc != prev) {
        atomicAdd(&agg[(size_t)prev * DD + c2], a);
        a = v; prev = rc;
      } else {
        a += v;
      }
    }
    atomicAdd(&agg[(size_t)prev * DD + c2], a);
  }
}

// ---------------------------------------------------------------------------
// out = h_d_prev + agg @ Wm  (fp32). 16 rows/block, LDS-staged agg (stride 72
// swizzle: conflict-free broadcast) + float4 Wm reads. Grid 3125.
// ---------------------------------------------------------------------------
__global__ __launch_bounds__(256) void final_out(
    const float* __restrict__ hd,
    const float* __restrict__ agg,
    const float* __restrict__ Wm,   // [64][64] fp32
    float* __restrict__ out)
{
  __shared__ float wmf[DD * DD];    // 16 KB
  __shared__ float arow[16 * 72];   // 4.5 KB, stride-72 swizzle
  int tid = threadIdx.x;
  const float4* wm4 = (const float4*)Wm;
  float4* wf4 = (float4*)wmf;
  #pragma unroll
  for (int i = tid; i < DD * DD / 4; i += 256) wf4[i] = wm4[i];

  int r0 = blockIdx.x * 16;
  {
    float4 av = *(const float4*)(agg + (size_t)r0 * DD + tid * 4);
    int rr = tid >> 4, cc = (tid & 15) * 4;       // tid*4 == rr*64 + cc
    *(float4*)&arow[rr * 72 + cc] = av;
  }
  __syncthreads();

  int row = tid >> 4;
  int cq  = (tid & 15) * 4;
  f32x4 acc = (f32x4){0, 0, 0, 0};
  #pragma unroll
  for (int k = 0; k < DD; ++k) {
    float a = arow[row * 72 + k];
    f32x4 w = *(const f32x4*)&wmf[k * DD + cq];
    acc += a * w;
  }
  size_t o = ((size_t)(r0 + row)) * DD + cq;
  f32x4 h = *(const f32x4*)(hd + o);
  *(f32x4*)(out + o) = h + acc;
}

// ---------------------------------------------------------------------------
extern "C" void kernel_launch(void* const* d_in, const int* in_sizes, int n_in,
                              void* d_out, int out_size, void* d_ws, size_t ws_size,
                              hipStream_t stream) {
  const float* hd = (const float*)d_in[0];
  const float* hs = (const float*)d_in[1];
  const float* ef = (const float*)d_in[2];
  const int* snd  = (const int*)d_in[3];
  const int* rcv  = (const int*)d_in[4];
  const float* W0 = (const float*)d_in[5];
  const float* b0 = (const float*)d_in[6];
  const float* W1 = (const float*)d_in[7];
  const float* b1 = (const float*)d_in[8];
  const float* W2 = (const float*)d_in[9];
  const float* b2 = (const float*)d_in[10];
  const float* Wm = (const float*)d_in[11];
  float* out      = (float*)d_out;

  char* ws = (char*)d_ws;
  float* agg  = (float*)ws;                                  // 12,800,000 B
  int* cnt    = (int*)(ws + 12800000);                       //    200,000 B
  int* cursor = (int*)(ws + 13000000);                       //    200,000 B
  unsigned short* WT0 = (unsigned short*)(ws + 13200000);    //     81,920 B
  unsigned short* WT1 = WT0 + KIN * HH;                      //     32,768 B
  unsigned short* WT2 = WT1 + HH * HH;                       //     16,384 B
  int* perm    = (int*)(ws + 13331072);                      //  3,200,000 B
  unsigned short* hdb = (unsigned short*)(ws + 16531072);    //  6,400,000 B
  unsigned short* hsb = hdb + (size_t)NN * DD;               //  6,400,000 B
                                                             // total ~29.3 MB
  hipMemsetAsync(cnt, 0, 400000, stream);    // cnt + cursor only (agg zeroed in prep_all)
  prep_all<<<3381, 256, 0, stream>>>(hd, hs, W0, W1, W2, rcv,
                                     hdb, hsb, WT0, WT1, WT2, cnt, agg);
  scan_bins<<<1, 1024, 0, stream>>>(cnt);
  scatter_perm<<<EE / 256, 256, 0, stream>>>(rcv, cnt, cursor, perm);
  edge_mlp<<<EE / TILE_E, 256, 0, stream>>>(hdb, hsb, ef, perm, snd, rcv,
                                            WT0, b0, WT1, b1, WT2, b2, agg);
  final_out<<<NN / 16, 256, 0, stream>>>(hd, agg, Wm, out);
}

// Round 5
// 521.012 us; speedup vs baseline: 1.5904x; 1.5904x over previous
//
#include <hip/hip_runtime.h>

// Problem constants (fixed by the reference)
#define NN   50000
#define EE   800000
#define DD   64
#define HH   128
#define KIN  320          // 5 * 64
#define TILE_E 128        // 128 edges/block, 512 threads, LDS 81920 B -> 2 blocks/CU

typedef __bf16 bf16x8 __attribute__((ext_vector_type(8)));
typedef float  f32x4  __attribute__((ext_vector_type(4)));

#if __has_builtin(__builtin_amdgcn_cvt_pk_bf16_f32)
typedef __bf16 bf16x2_t __attribute__((ext_vector_type(2)));
__device__ __forceinline__ unsigned int pk2(float a, float b) {
  union { bf16x2_t v; unsigned int u; } cv;
  cv.v = __builtin_amdgcn_cvt_pk_bf16_f32(a, b);
  return cv.u;
}
__device__ __forceinline__ unsigned short f2bf(float a) {
  return (unsigned short)(pk2(a, a) & 0xFFFFu);
}
#else
__device__ __forceinline__ unsigned short f2bf(float f) {
  union { float f; unsigned int u; } v; v.f = f;
  unsigned int u = v.u + 0x7FFFu + ((v.u >> 16) & 1u);   // RTNE
  return (unsigned short)(u >> 16);
}
__device__ __forceinline__ unsigned int pk2(float a, float b) {
  return (unsigned int)f2bf(a) | ((unsigned int)f2bf(b) << 16);
}
#endif

__device__ __forceinline__ float bf2f(unsigned short b) {
  union { unsigned int u; float f; } v; v.u = ((unsigned int)b) << 16; return v.f;
}

// Packed, pad-free psi layout in 16B units: unit = ((row>>4)*10 + (kk>>5))*64
//                                                + (row&15)*4 + ((kk>>3)&3)
// u16 index for (row in [0,128), kk in [0,320)):
__device__ __forceinline__ int psiIdx(int row, int kk) {
  return ((((row >> 4) * 10 + (kk >> 5)) << 6) + ((row & 15) << 2) + ((kk >> 3) & 3)) * 8
         + (kk & 7);
}

// ---------------------------------------------------------------------------
// Fused prep: node tables fp32->bf16, weight transpose fp32->bf16 ([n][k] so
// MFMA B-fragments are 16B runs), agg zeroing. Grid 3381 x 256.
// ---------------------------------------------------------------------------
__global__ __launch_bounds__(256) void prep_all(
    const float* __restrict__ hd, const float* __restrict__ hs,
    const float* __restrict__ W0, const float* __restrict__ W1,
    const float* __restrict__ W2,
    unsigned short* __restrict__ hdb, unsigned short* __restrict__ hsb,
    unsigned short* __restrict__ WT0, unsigned short* __restrict__ WT1,
    unsigned short* __restrict__ WT2, float* __restrict__ agg) {
  int b = blockIdx.x;
  int t = b * 256 + threadIdx.x;
  if (b < 3125) {                          // t in [0, 800000)
    *(float4*)(agg + (size_t)t * 4) = (float4){0.f, 0.f, 0.f, 0.f};  // zero agg
    const int n = NN * DD / 8;             // 400000
    const float* src; unsigned short* dst; int i;
    if (t < n) { src = hd; dst = hdb; i = t; }
    else       { src = hs; dst = hsb; i = t - n; }
    float4 a = *(const float4*)(src + (size_t)i * 8);
    float4 c = *(const float4*)(src + (size_t)i * 8 + 4);
    uint4 w;
    w.x = pk2(a.x, a.y); w.y = pk2(a.z, a.w);
    w.z = pk2(c.x, c.y); w.w = pk2(c.z, c.w);
    *(uint4*)(dst + (size_t)i * 8) = w;
  } else {                                 // weights: u in [0, 65536)
    int u = t - 3125 * 256;
    if (u < KIN * HH) {
      int k = u / HH, n2 = u % HH;
      WT0[n2 * KIN + k] = f2bf(W0[u]);
    } else if (u < KIN * HH + HH * HH) {
      int v = u - KIN * HH; int k = v / HH, n2 = v % HH;
      WT1[n2 * HH + k] = f2bf(W1[v]);
    } else {
      int v = u - KIN * HH - HH * HH; int k = v / DD, n2 = v % DD;
      WT2[n2 * HH + k] = f2bf(W2[v]);
    }
  }
}

// ---------------------------------------------------------------------------
// Fused edge kernel. 512 threads (8 waves), 128 edges/block, LDS = 81920 B
// -> exactly 2 blocks/CU (16 waves/CU, same occupancy as the best-known
// config but half the blocks: the ~13K-cycle per-block toll halves per edge).
// Each wave owns 16 output cols. Gather loads batched to registers; weight
// fragments preloaded into registers BEFORE the preceding barrier so L2
// latency overlaps barrier wait. Direct fp32 atomicAdd scatter.
// ---------------------------------------------------------------------------
__global__ __launch_bounds__(512, 4) void edge_mlp(
    const unsigned short* __restrict__ hdb,  // h_d_prev [N][64] bf16
    const unsigned short* __restrict__ hsb,  // h_s      [N][64] bf16
    const float* __restrict__ ef,            // edge_feat[E][64] fp32
    const int* __restrict__ snd,
    const int* __restrict__ rcv,
    const unsigned short* __restrict__ WT0,  // [128][320] bf16
    const float* __restrict__ b0,            // [128]
    const unsigned short* __restrict__ WT1,  // [128][128] bf16
    const float* __restrict__ b1,            // [128]
    const unsigned short* __restrict__ WT2,  // [64][128] bf16
    const float* __restrict__ b2,            // [64]
    float* __restrict__ agg)                 // [N][64] fp32
{
  __shared__ __align__(16) unsigned short psi[TILE_E * KIN];  // 81920 B exactly

  const int tid  = threadIdx.x;
  const int e0   = blockIdx.x * TILE_E;
  const int wv   = tid >> 6;        // 0..7
  const int lane = tid & 63;
  const int ln   = lane & 15;
  const int quad = lane >> 4;
  const int mtb  = (wv >> 2) * 4;   // epilogue row-tile base: 0 or 4

  // Receiver indices this lane scatters to (16 rows; hidden under gather).
  int ridx[16];
  #pragma unroll
  for (int mt = 0; mt < 4; ++mt)
    #pragma unroll
    for (int i = 0; i < 4; ++i)
      ridx[mt * 4 + i] = rcv[e0 + (mtb + mt) * 16 + quad * 4 + i];

  // Gather: 10 jobs/thread (5 segs x 2 edge-halves), all loads issued into
  // registers first (one HBM round-trip), then written to LDS.
  // segs 0-3: bf16 table rows (16B/job). seg 4: ef fp32, pack to bf16.
  {
    const int eA = tid >> 3;          // [0,64)
    const int eB = eA + 64;           // [64,128)
    const int c  = tid & 7;           // 16B chunk of the 320-elem row
    const int siA = snd[e0 + eA], siB = snd[e0 + eB];
    const int riA = rcv[e0 + eA], riB = rcv[e0 + eB];
    uint4 w[10];
    #pragma unroll
    for (int i = 0; i < 10; ++i) {
      const int seg = i >> 1;                    // compile-time 0..4
      if (seg < 4) {
        const unsigned short* tb = (seg & 2) ? hdb : hsb;   // 0,1=h_s  2,3=h_d
        int ix = (seg & 1) ? ((i & 1) ? riB : riA)
                           : ((i & 1) ? siB : siA);
        w[i] = *(const uint4*)(tb + (size_t)ix * DD + c * 8);
      } else {
        const int e = (i & 1) ? eB : eA;
        const float* src = ef + (size_t)(e0 + e) * DD + c * 8;
        float4 v0 = *(const float4*)(src);
        float4 v1 = *(const float4*)(src + 4);
        w[i].x = pk2(v0.x, v0.y); w[i].y = pk2(v0.z, v0.w);
        w[i].z = pk2(v1.x, v1.y); w[i].w = pk2(v1.z, v1.w);
      }
    }
    #pragma unroll
    for (int i = 0; i < 10; ++i) {
      const int seg = i >> 1;
      const int e   = (i & 1) ? eB : eA;
      int unit = (((e >> 4) * 10 + seg * 2 + (c >> 2)) << 6) + ((e & 15) << 2) + (c & 3);
      *(uint4*)(&psi[unit * 8]) = w[i];
    }
  }

  const int col = wv * 16 + ln;       // this wave's output column, layers 0/1

  // Preload ALL Layer-0 weight fragments (L2 latency overlaps barrier wait).
  bf16x8 wf[10];
  {
    const unsigned short* wb = WT0 + col * KIN + quad * 8;
    #pragma unroll
    for (int k0 = 0; k0 < 10; ++k0) wf[k0] = *(const bf16x8*)(wb + k0 * 32);
  }
  __syncthreads();

  f32x4 acc[8];

  // ------------------ Layer 0: [128,320] @ [320,128] -----------------------
  #pragma unroll
  for (int m = 0; m < 8; ++m) acc[m] = (f32x4){0,0,0,0};
  #pragma unroll
  for (int k0 = 0; k0 < 10; ++k0)
    #pragma unroll
    for (int mt = 0; mt < 8; ++mt) {
      bf16x8 af = *(const bf16x8*)(&psi[(((mt * 10 + k0) << 6) + (ln << 2) + quad) * 8]);
      acc[mt] = __builtin_amdgcn_mfma_f32_16x16x32_bf16(af, wf[k0], acc[mt], 0, 0, 0);
    }
  __syncthreads();          // psi input reads done -> safe to overwrite kk[0,128)

  // h1 -> kk [0,128)
  {
    float bv = b0[col];
    #pragma unroll
    for (int mt = 0; mt < 8; ++mt)
      #pragma unroll
      for (int i = 0; i < 4; ++i) {
        int row = mt * 16 + quad * 4 + i;
        float v = acc[mt][i] + bv; v = v > 0.f ? v : 0.f;
        psi[psiIdx(row, col)] = f2bf(v);
      }
  }
  // Preload Layer-1 weight fragments before the barrier.
  bf16x8 wg[4];
  {
    const unsigned short* wb = WT1 + col * HH + quad * 8;
    #pragma unroll
    for (int k0 = 0; k0 < 4; ++k0) wg[k0] = *(const bf16x8*)(wb + k0 * 32);
  }
  __syncthreads();

  // ------------------ Layer 1: [128,128] @ [128,128] -----------------------
  #pragma unroll
  for (int m = 0; m < 8; ++m) acc[m] = (f32x4){0,0,0,0};
  #pragma unroll
  for (int k0 = 0; k0 < 4; ++k0)
    #pragma unroll
    for (int mt = 0; mt < 8; ++mt) {
      bf16x8 af = *(const bf16x8*)(&psi[(((mt * 10 + k0) << 6) + (ln << 2) + quad) * 8]);
      acc[mt] = __builtin_amdgcn_mfma_f32_16x16x32_bf16(af, wg[k0], acc[mt], 0, 0, 0);
    }
  __syncthreads();          // h1 reads done -> overwrite with h2

  {
    float bv = b1[col];
    #pragma unroll
    for (int mt = 0; mt < 8; ++mt)
      #pragma unroll
      for (int i = 0; i < 4; ++i) {
        int row = mt * 16 + quad * 4 + i;
        float v = acc[mt][i] + bv; v = v > 0.f ? v : 0.f;
        psi[psiIdx(row, col)] = f2bf(v);
      }
  }
  // Preload Layer-2 weight fragments before the barrier.
  const int col2 = (wv & 3) * 16 + ln;   // waves 0-3 & 4-7 pair over 64 cols
  bf16x8 wh[4];
  {
    const unsigned short* wb = WT2 + col2 * HH + quad * 8;
    #pragma unroll
    for (int k0 = 0; k0 < 4; ++k0) wh[k0] = *(const bf16x8*)(wb + k0 * 32);
  }
  __syncthreads();

  // ---------- Layer 2: [128,128] @ [128,64] + s_ij + atomic scatter --------
  {
    f32x4 acc2[4];
    #pragma unroll
    for (int m = 0; m < 4; ++m) acc2[m] = (f32x4){0,0,0,0};
    #pragma unroll
    for (int k0 = 0; k0 < 4; ++k0)
      #pragma unroll
      for (int m = 0; m < 4; ++m) {
        int mt = mtb + m;
        bf16x8 af = *(const bf16x8*)(&psi[(((mt * 10 + k0) << 6) + (ln << 2) + quad) * 8]);
        acc2[m] = __builtin_amdgcn_mfma_f32_16x16x32_bf16(af, wh[k0], acc2[m], 0, 0, 0);
      }
    float bv = b2[col2];
    #pragma unroll
    for (int m = 0; m < 4; ++m)
      #pragma unroll
      for (int i = 0; i < 4; ++i) {
        int row = (mtb + m) * 16 + quad * 4 + i;
        float p  = acc2[m][i] + bv; p = p > 0.f ? p : 0.f;
        float di = bf2f(psi[psiIdx(row, 128 + col2)]);   // h_d[sender]
        float dj = bf2f(psi[psiIdx(row, 192 + col2)]);   // h_d[receiver]
        float s  = p * (dj - di);
        atomicAdd(&agg[(size_t)ridx[m * 4 + i] * DD + col2], s);
      }
  }
}

// ---------------------------------------------------------------------------
// out = h_d_prev + agg @ Wm  (fp32). 16 rows/block, LDS-staged agg (stride 72
// swizzle: conflict-free broadcast) + float4 Wm reads. Grid 3125.
// ---------------------------------------------------------------------------
__global__ __launch_bounds__(256) void final_out(
    const float* __restrict__ hd,
    const float* __restrict__ agg,
    const float* __restrict__ Wm,   // [64][64] fp32
    float* __restrict__ out)
{
  __shared__ float wmf[DD * DD];    // 16 KB
  __shared__ float arow[16 * 72];   // 4.5 KB, stride-72 swizzle
  int tid = threadIdx.x;
  const float4* wm4 = (const float4*)Wm;
  float4* wf4 = (float4*)wmf;
  #pragma unroll
  for (int i = tid; i < DD * DD / 4; i += 256) wf4[i] = wm4[i];

  int r0 = blockIdx.x * 16;
  {
    float4 av = *(const float4*)(agg + (size_t)r0 * DD + tid * 4);
    int rr = tid >> 4, cc = (tid & 15) * 4;       // tid*4 == rr*64 + cc
    *(float4*)&arow[rr * 72 + cc] = av;
  }
  __syncthreads();

  int row = tid >> 4;
  int cq  = (tid & 15) * 4;
  f32x4 acc = (f32x4){0, 0, 0, 0};
  #pragma unroll
  for (int k = 0; k < DD; ++k) {
    float a = arow[row * 72 + k];
    f32x4 w = *(const f32x4*)&wmf[k * DD + cq];
    acc += a * w;
  }
  size_t o = ((size_t)(r0 + row)) * DD + cq;
  f32x4 h = *(const f32x4*)(hd + o);
  *(f32x4*)(out + o) = h + acc;
}

// ---------------------------------------------------------------------------
extern "C" void kernel_launch(void* const* d_in, const int* in_sizes, int n_in,
                              void* d_out, int out_size, void* d_ws, size_t ws_size,
                              hipStream_t stream) {
  const float* hd = (const float*)d_in[0];
  const float* hs = (const float*)d_in[1];
  const float* ef = (const float*)d_in[2];
  const int* snd  = (const int*)d_in[3];
  const int* rcv  = (const int*)d_in[4];
  const float* W0 = (const float*)d_in[5];
  const float* b0 = (const float*)d_in[6];
  const float* W1 = (const float*)d_in[7];
  const float* b1 = (const float*)d_in[8];
  const float* W2 = (const float*)d_in[9];
  const float* b2 = (const float*)d_in[10];
  const float* Wm = (const float*)d_in[11];
  float* out      = (float*)d_out;

  char* ws = (char*)d_ws;
  float* agg = (float*)ws;                                   // 12,800,000 B
  unsigned short* WT0 = (unsigned short*)(ws + 12800000);    //     81,920 B
  unsigned short* WT1 = WT0 + KIN * HH;                      //     32,768 B
  unsigned short* WT2 = WT1 + HH * HH;                       //     16,384 B
  unsigned short* hdb = WT2 + HH * DD;                       //  6,400,000 B
  unsigned short* hsb = hdb + (size_t)NN * DD;               //  6,400,000 B
                                                             // total ~25.8 MB
  prep_all<<<3381, 256, 0, stream>>>(hd, hs, W0, W1, W2,
                                     hdb, hsb, WT0, WT1, WT2, agg);
  edge_mlp<<<EE / TILE_E, 512, 0, stream>>>(hdb, hsb, ef, snd, rcv,
                                            WT0, b0, WT1, b1, WT2, b2, agg);
  final_out<<<NN / 16, 256, 0, stream>>>(hd, agg, Wm, out);
}